// Round 8
// baseline (1129.218 us; speedup 1.0000x reference)
//
#include <hip/hip_runtime.h>
#include <hip/hip_bf16.h>

#define H      128
#define NNODE  50000
#define NLINK  100000
#define NEDGE  600000
#define NGRAPH 32
#define NLAYER 4
#define ROUNDL 100032   // NLINK rounded to 64
#define ROUNDN 50048    // NNODE rounded to 64

typedef short  bf16x8 __attribute__((ext_vector_type(8)));
typedef ushort u16x8  __attribute__((ext_vector_type(8)));
typedef float  f32x4  __attribute__((ext_vector_type(4)));

__device__ __forceinline__ ushort f2bf(float f) {
    uint32_t u = __float_as_uint(f);
    uint32_t r = (u + 0x7fff + ((u >> 16) & 1)) >> 16;   // RNE
    return (ushort)r;
}
__device__ __forceinline__ float bf2f(ushort h) {
    return __uint_as_float(((uint32_t)h) << 16);
}
// split: hi = truncation (top 16 bits), lo = RNE(f - hi). |f - hi - lo| <= 2^-16 |f|
__device__ __forceinline__ ushort2 split2(float f) {
    uint32_t u = __float_as_uint(f);
    ushort hi = (ushort)(u >> 16);
    float r = f - __uint_as_float(u & 0xffff0000u);
    ushort2 out;
    out.x = hi;
    out.y = f2bf(r);
    return out;
}

// ---------------- CSR build ----------------

__global__ void count_edges_k(const int* __restrict__ nl_dst, const int* __restrict__ ln_dst,
                              int* __restrict__ cnt_link, int* __restrict__ cnt_node) {
    int i = blockIdx.x * blockDim.x + threadIdx.x;
    int stride = gridDim.x * blockDim.x;
    for (; i < NEDGE; i += stride) {
        atomicAdd(&cnt_link[nl_dst[i]], 1);
        atomicAdd(&cnt_node[ln_dst[i]], 1);
    }
}

// merged link+node block sums (1024 elems/block)
__global__ void scan_sums_k(const int* __restrict__ cnt_link, const int* __restrict__ cnt_node,
                            int* __restrict__ bsums, int nbL) {
    __shared__ int sd[256];
    int b = blockIdx.x;
    const int* in;
    int n, lb;
    if (b < nbL) { in = cnt_link; n = NLINK; lb = b; }
    else         { in = cnt_node; n = NNODE; lb = b - nbL; }
    int base = lb * 1024;
    int s = 0;
    for (int i = threadIdx.x; i < 1024; i += 256) {
        int idx = base + i;
        if (idx < n) s += in[idx];
    }
    sd[threadIdx.x] = s;
    __syncthreads();
    for (int off = 128; off; off >>= 1) {
        if (threadIdx.x < off) sd[threadIdx.x] += sd[threadIdx.x + off];
        __syncthreads();
    }
    if (threadIdx.x == 0) bsums[b] = sd[0];
}

// two independent exclusive scans over bsums[0,len0) and bsums[len0, len0+len1)
__global__ void scan_bsums2_k(int* __restrict__ bsums, int len0, int len1) {
    __shared__ int tmp[2][1024];
    int t = threadIdx.x;
    int base = 0;
    for (int seg = 0; seg < 2; ++seg) {
        int len = seg ? len1 : len0;
        int v = (t < len) ? bsums[base + t] : 0;
        tmp[0][t] = v;
        __syncthreads();
        int src = 0;
        for (int off = 1; off < 1024; off <<= 1) {
            int nv = tmp[src][t] + ((t >= off) ? tmp[src][t - off] : 0);
            tmp[src ^ 1][t] = nv;
            __syncthreads();
            src ^= 1;
        }
        if (t < len) bsums[base + t] = tmp[src][t] - v;   // exclusive
        __syncthreads();
        base += len0;
    }
}

__global__ void scan_final_k(const int* __restrict__ cnt_link, const int* __restrict__ cnt_node,
                             const int* __restrict__ bsums,
                             int* __restrict__ rowp_link, int* __restrict__ rowp_node, int nbL) {
    __shared__ int tmp[2][256];
    int b = blockIdx.x, t = threadIdx.x;
    const int* in;
    int* outp;
    int n, lb;
    if (b < nbL) { in = cnt_link; outp = rowp_link; n = NLINK; lb = b; }
    else         { in = cnt_node; outp = rowp_node; n = NNODE; lb = b - nbL; }
    int base = lb * 1024 + t * 4;
    int vals[4];
    int s = 0;
#pragma unroll
    for (int j = 0; j < 4; ++j) {
        int idx = base + j;
        vals[j] = (idx < n) ? in[idx] : 0;
        s += vals[j];
    }
    tmp[0][t] = s;
    __syncthreads();
    int src = 0;
    for (int off = 1; off < 256; off <<= 1) {
        int nv = tmp[src][t] + ((t >= off) ? tmp[src][t - off] : 0);
        tmp[src ^ 1][t] = nv;
        __syncthreads();
        src ^= 1;
    }
    int run = bsums[b] + tmp[src][t] - s;
#pragma unroll
    for (int j = 0; j < 4; ++j) {
        int idx = base + j;
        if (idx < n) outp[idx] = run;
        run += vals[j];
    }
    if (lb == 0 && t == 0) outp[n] = NEDGE;
}

__global__ void fill_csr2_k(const int* __restrict__ nl_dst, const int* __restrict__ nl_src,
                            const int* __restrict__ ln_dst, const int* __restrict__ ln_src,
                            const int* __restrict__ rowp_link, const int* __restrict__ rowp_node,
                            int* __restrict__ cur_link, int* __restrict__ cur_node,
                            int* __restrict__ col_nl, int* __restrict__ col_ln) {
    int half = gridDim.x >> 1;
    bool isL = blockIdx.x < half;
    const int* dst = isL ? nl_dst : ln_dst;
    const int* srcA = isL ? nl_src : ln_src;
    const int* rowp = isL ? rowp_link : rowp_node;
    int* cursor = isL ? cur_link : cur_node;
    int* col = isL ? col_nl : col_ln;
    int b = isL ? blockIdx.x : blockIdx.x - half;
    int i = b * 256 + threadIdx.x;
    int stride = half * 256;
    for (; i < NEDGE; i += stride) {
        int d = dst[i];
        int pos = rowp[d] + atomicAdd(&cursor[d], 1);
        col[pos] = srcA[i];
    }
}

__global__ void batch_ranges_k(const int* __restrict__ batch, int* __restrict__ gstart,
                               float* __restrict__ ginv) {
    __shared__ int ss[NGRAPH + 1];
    int g = threadIdx.x;
    if (g <= NGRAPH) {
        int lo = 0, hi = NLINK;
        while (lo < hi) {
            int mid = (lo + hi) >> 1;
            if (batch[mid] < g) lo = mid + 1; else hi = mid;
        }
        ss[g] = lo;
        gstart[g] = lo;
    }
    __syncthreads();
    if (g < NGRAPH) {
        int c = ss[g + 1] - ss[g];
        ginv[g] = 1.0f / (float)(c > 0 ? c : 1);
    }
}

// ---------------- fp32 -> bf16 hi/lo planes (plain row-major) ----------------
__global__ void split_k(const float* __restrict__ src, ushort* __restrict__ hi,
                        ushort* __restrict__ lo, int n) {
    int id = blockIdx.x * 256 + threadIdx.x;   // 8-elem unit id
    if (id >= n * 16) return;
    int row = id >> 4, u = id & 15;
    const float4* s = reinterpret_cast<const float4*>(src + (size_t)row * H + u * 8);
    float4 v0 = s[0], v1 = s[1];
    u16x8 h8, l8;
    ushort2 r;
    r = split2(v0.x); h8[0] = r.x; l8[0] = r.y;
    r = split2(v0.y); h8[1] = r.x; l8[1] = r.y;
    r = split2(v0.z); h8[2] = r.x; l8[2] = r.y;
    r = split2(v0.w); h8[3] = r.x; l8[3] = r.y;
    r = split2(v1.x); h8[4] = r.x; l8[4] = r.y;
    r = split2(v1.y); h8[5] = r.x; l8[5] = r.y;
    r = split2(v1.z); h8[6] = r.x; l8[6] = r.y;
    r = split2(v1.w); h8[7] = r.x; l8[7] = r.y;
    int off = row * 128 + u * 8;
    *reinterpret_cast<u16x8*>(hi + off) = h8;
    *reinterpret_cast<u16x8*>(lo + off) = l8;
}

// ---------------- W fragment prep (split bf16, MFMA B-frag order) ----------------
__global__ void prep_w_k(const float* __restrict__ W_nl, const float* __restrict__ W_ln,
                         ushort* __restrict__ Whf, ushort* __restrict__ Wlf) {
    int mat = blockIdx.x;                  // mat = layer*2 + rel (rel 0=nl, 1=ln)
    int layer = mat >> 1, rel = mat & 1;
    const float* W = (rel ? W_ln : W_nl) + (size_t)layer * 2 * H * H;
    ushort* wh = Whf + (size_t)mat * 32768;
    ushort* wl = Wlf + (size_t)mat * 32768;
    for (int f = threadIdx.x; f < 32768; f += 256) {
        int j = f & 7;
        int lane = (f >> 3) & 63;
        int nsub = (f >> 9) & 7;
        int ks = f >> 12;
        int k = ks * 32 + (lane >> 4) * 8 + j;
        int col = nsub * 16 + (lane & 15);
        float w = W[(size_t)k * H + col];
        ushort hi = f2bf(w);
        ushort lo = f2bf(w - bf2f(hi));
        wh[f] = hi;
        wl[f] = lo;
    }
}

// ---------------- mean aggregation: CSR gather over hi/lo planes ----------------
__global__ __launch_bounds__(256) void agg_k(
    const ushort* __restrict__ shi, const ushort* __restrict__ slo,
    const int* __restrict__ rowp, const int* __restrict__ colx,
    ushort* __restrict__ dhi, ushort* __restrict__ dlo, int ndst) {
    int g = blockIdx.x * 16 + (threadIdx.x >> 4);
    int l16 = threadIdx.x & 15;
    if (g >= ndst) return;
    int rs = rowp[g], re = rowp[g + 1];
    float a[8] = {0.f, 0.f, 0.f, 0.f, 0.f, 0.f, 0.f, 0.f};
    int e = rs;
    for (; e + 2 <= re; e += 2) {
        int c0 = colx[e], c1 = colx[e + 1];
        size_t o0 = (size_t)c0 * 128 + l16 * 8;
        size_t o1 = (size_t)c1 * 128 + l16 * 8;
        u16x8 h0 = *reinterpret_cast<const u16x8*>(shi + o0);
        u16x8 l0 = *reinterpret_cast<const u16x8*>(slo + o0);
        u16x8 h1 = *reinterpret_cast<const u16x8*>(shi + o1);
        u16x8 l1 = *reinterpret_cast<const u16x8*>(slo + o1);
#pragma unroll
        for (int j = 0; j < 8; ++j)
            a[j] += (bf2f(h0[j]) + bf2f(l0[j])) + (bf2f(h1[j]) + bf2f(l1[j]));
    }
    if (e < re) {
        int c0 = colx[e];
        size_t o0 = (size_t)c0 * 128 + l16 * 8;
        u16x8 h0 = *reinterpret_cast<const u16x8*>(shi + o0);
        u16x8 l0 = *reinterpret_cast<const u16x8*>(slo + o0);
#pragma unroll
        for (int j = 0; j < 8; ++j)
            a[j] += bf2f(h0[j]) + bf2f(l0[j]);
    }
    int c = re - rs;
    float inv = 1.0f / (float)(c > 0 ? c : 1);
    u16x8 h8, l8;
#pragma unroll
    for (int j = 0; j < 8; ++j) {
        ushort2 hl = split2(a[j] * inv);
        h8[j] = hl.x; l8[j] = hl.y;
    }
    int off = g * 128 + l16 * 8;
    *reinterpret_cast<u16x8*>(dhi + off) = h8;
    *reinterpret_cast<u16x8*>(dlo + off) = l8;
}

// ---------------- GEMM: relu([agg | self] @ W + b), split-bf16 MFMA ----------------
// LDS-free: 64-row tile, 4 waves; wave w computes cols [w*32, w*32+32).
// A-fragments loaded straight from global (16 rows x 64B contiguous per wave-load,
// L1-served across the 4 waves). No barriers; waves fully independent.
__global__ __launch_bounds__(256) void gemm_k(
    const ushort* __restrict__ ahi, const ushort* __restrict__ alo,
    const ushort* __restrict__ shi, const ushort* __restrict__ slo,
    const ushort* __restrict__ wh, const ushort* __restrict__ wl,
    const float* __restrict__ bias,
    ushort* __restrict__ ohi, ushort* __restrict__ olo, int ndst) {
    const int lane = threadIdx.x & 63;
    const int wave = threadIdx.x >> 6;
    const int l15 = lane & 15;
    const int lhi = lane >> 4;
    const int t0 = blockIdx.x * 64;

    const bf16x8* __restrict__ wh8 = reinterpret_cast<const bf16x8*>(wh);
    const bf16x8* __restrict__ wl8 = reinterpret_cast<const bf16x8*>(wl);

    f32x4 acc[4][2];
#pragma unroll
    for (int rs = 0; rs < 4; ++rs)
#pragma unroll
        for (int c = 0; c < 2; ++c)
            acc[rs][c] = (f32x4){0.f, 0.f, 0.f, 0.f};

#pragma unroll 2
    for (int ks = 0; ks < 8; ++ks) {
        const ushort* __restrict__ ph = (ks < 4) ? ahi : shi;
        const ushort* __restrict__ pl = (ks < 4) ? alo : slo;
        const int ko = (ks & 3) * 32 + lhi * 8;
        bf16x8 ah[4], al[4];
#pragma unroll
        for (int rs = 0; rs < 4; ++rs) {
            size_t off = (size_t)(t0 + rs * 16 + l15) * 128 + ko;
            ah[rs] = *reinterpret_cast<const bf16x8*>(ph + off);
            al[rs] = *reinterpret_cast<const bf16x8*>(pl + off);
        }
        int fi = (ks * 8 + wave * 2) * 64 + lane;
        bf16x8 bh0 = wh8[fi], bl0 = wl8[fi];
        bf16x8 bh1 = wh8[fi + 64], bl1 = wl8[fi + 64];
#pragma unroll
        for (int rs = 0; rs < 4; ++rs) {
            acc[rs][0] = __builtin_amdgcn_mfma_f32_16x16x32_bf16(ah[rs], bh0, acc[rs][0], 0, 0, 0);
            acc[rs][0] = __builtin_amdgcn_mfma_f32_16x16x32_bf16(ah[rs], bl0, acc[rs][0], 0, 0, 0);
            acc[rs][0] = __builtin_amdgcn_mfma_f32_16x16x32_bf16(al[rs], bh0, acc[rs][0], 0, 0, 0);
            acc[rs][1] = __builtin_amdgcn_mfma_f32_16x16x32_bf16(ah[rs], bh1, acc[rs][1], 0, 0, 0);
            acc[rs][1] = __builtin_amdgcn_mfma_f32_16x16x32_bf16(ah[rs], bl1, acc[rs][1], 0, 0, 0);
            acc[rs][1] = __builtin_amdgcn_mfma_f32_16x16x32_bf16(al[rs], bh1, acc[rs][1], 0, 0, 0);
        }
    }

    const float bv0 = bias[wave * 32 + l15];
    const float bv1 = bias[wave * 32 + 16 + l15];
#pragma unroll
    for (int rs = 0; rs < 4; ++rs) {
#pragma unroll
        for (int c = 0; c < 2; ++c) {
            int col = wave * 32 + c * 16 + l15;
            float bb = c ? bv1 : bv0;
#pragma unroll
            for (int reg = 0; reg < 4; ++reg) {
                int row = t0 + rs * 16 + lhi * 4 + reg;
                if (row < ndst) {
                    float v = fmaxf(acc[rs][c][reg] + bb, 0.f);
                    ushort2 hl = split2(v);
                    size_t off = (size_t)row * 128 + col;
                    ohi[off] = hl.x;
                    olo[off] = hl.y;
                }
            }
        }
    }
}

// ---------------- final global mean pool over links ----------------
__global__ __launch_bounds__(256) void pool_k(
    const ushort* __restrict__ xhi, const ushort* __restrict__ xlo,
    const int* __restrict__ gstart, const float* __restrict__ ginv,
    float* __restrict__ out) {
    int g = blockIdx.x >> 3, chunk = blockIdx.x & 7;
    int s = gstart[g], e = gstart[g + 1];
    int rl = threadIdx.x >> 4, l16 = threadIdx.x & 15;
    float a[8] = {0.f, 0.f, 0.f, 0.f, 0.f, 0.f, 0.f, 0.f};
    for (int r = s + chunk * 16 + rl; r < e; r += 128) {
        int off = r * 128 + l16 * 8;
        u16x8 h = *reinterpret_cast<const u16x8*>(xhi + off);
        u16x8 l = *reinterpret_cast<const u16x8*>(xlo + off);
#pragma unroll
        for (int j = 0; j < 8; ++j) a[j] += bf2f(h[j]) + bf2f(l[j]);
    }
    __shared__ float sm[16][128];
#pragma unroll
    for (int j = 0; j < 8; ++j) sm[rl][l16 * 8 + j] = a[j];
    __syncthreads();
    for (int st = 8; st; st >>= 1) {
        if (rl < st) {
#pragma unroll
            for (int j = 0; j < 8; ++j)
                sm[rl][l16 * 8 + j] += sm[rl + st][l16 * 8 + j];
        }
        __syncthreads();
    }
    if (rl == 0) {
        float gi = ginv[g];
#pragma unroll
        for (int j = 0; j < 8; ++j)
            atomicAdd(&out[g * H + l16 * 8 + j], sm[0][l16 * 8 + j] * gi);
    }
}

// ---------------- host ----------------

extern "C" void kernel_launch(void* const* d_in, const int* in_sizes, int n_in,
                              void* d_out, int out_size, void* d_ws, size_t ws_size,
                              hipStream_t stream) {
    const float* x_node = (const float*)d_in[0];
    const float* x_link = (const float*)d_in[1];
    const int* nl_src = (const int*)d_in[2];
    const int* nl_dst = (const int*)d_in[3];
    const int* ln_src = (const int*)d_in[4];
    const int* ln_dst = (const int*)d_in[5];
    const int* batch = (const int*)d_in[6];
    const float* W_nl = (const float*)d_in[7];
    const float* b_nl = (const float*)d_in[8];
    const float* W_ln = (const float*)d_in[9];
    const float* b_ln = (const float*)d_in[10];
    float* out = (float*)d_out;

    char* ws = (char*)d_ws;
    size_t off = 0;
    auto alloc = [&](size_t bytes) -> void* {
        void* pp = ws + off;
        off += (bytes + 255) & ~(size_t)255;
        return pp;
    };
    const size_t LP = (size_t)ROUNDL * H * 2;   // link plane bytes
    const size_t NP = (size_t)ROUNDN * H * 2;   // node plane bytes
    ushort* xlh[2] = {(ushort*)alloc(LP), (ushort*)alloc(LP)};
    ushort* xll[2] = {(ushort*)alloc(LP), (ushort*)alloc(LP)};
    ushort* xnh[2] = {(ushort*)alloc(NP), (ushort*)alloc(NP)};
    ushort* xnl[2] = {(ushort*)alloc(NP), (ushort*)alloc(NP)};
    int* rowp_link = (int*)alloc((size_t)(NLINK + 1) * 4);
    int* rowp_node = (int*)alloc((size_t)(NNODE + 1) * 4);
    int* col_nl = (int*)alloc((size_t)NEDGE * 4);
    int* col_ln = (int*)alloc((size_t)NEDGE * 4);
    int* cnts = (int*)alloc((size_t)(2 * (NLINK + NNODE)) * 4);
    int* cnt_link = cnts;
    int* cnt_node = cnts + NLINK;
    int* cur_link = cnt_node + NNODE;
    int* cur_node = cur_link + NLINK;
    int* bsums = (int*)alloc(1024 * 4);
    int* gstart = (int*)alloc((NGRAPH + 1) * 4);
    float* ginv = (float*)alloc(NGRAPH * 4);
    ushort* Whf = (ushort*)alloc((size_t)8 * 32768 * 2);
    ushort* Wlf = (ushort*)alloc((size_t)8 * 32768 * 2);

    if (off > ws_size) return;

    hipMemsetAsync(cnts, 0, (size_t)(2 * (NLINK + NNODE)) * 4, stream);
    hipMemsetAsync(out, 0, (size_t)NGRAPH * H * 4, stream);

    prep_w_k<<<8, 256, 0, stream>>>(W_nl, W_ln, Whf, Wlf);

    split_k<<<NLINK * 16 / 256, 256, 0, stream>>>(x_link, xlh[0], xll[0], NLINK);
    split_k<<<NNODE * 16 / 256, 256, 0, stream>>>(x_node, xnh[0], xnl[0], NNODE);

    count_edges_k<<<1024, 256, 0, stream>>>(nl_dst, ln_dst, cnt_link, cnt_node);

    const int nbL = (NLINK + 1023) / 1024;   // 98
    const int nbN = (NNODE + 1023) / 1024;   // 49
    scan_sums_k<<<nbL + nbN, 256, 0, stream>>>(cnt_link, cnt_node, bsums, nbL);
    scan_bsums2_k<<<1, 1024, 0, stream>>>(bsums, nbL, nbN);
    scan_final_k<<<nbL + nbN, 256, 0, stream>>>(cnt_link, cnt_node, bsums,
                                                rowp_link, rowp_node, nbL);

    fill_csr2_k<<<2048, 256, 0, stream>>>(nl_dst, nl_src, ln_dst, ln_src,
                                          rowp_link, rowp_node, cur_link, cur_node,
                                          col_nl, col_ln);

    batch_ranges_k<<<1, 64, 0, stream>>>(batch, gstart, ginv);

    int cur = 0;
    for (int i = 0; i < NLAYER; ++i) {
        int nxt = cur ^ 1;
        int matL = i * 2 + 0;
        int matN = i * 2 + 1;
        // link relation: agg from node feats -> in-place into link output buffer
        agg_k<<<(NLINK + 15) / 16, 256, 0, stream>>>(
            xnh[cur], xnl[cur], rowp_link, col_nl, xlh[nxt], xll[nxt], NLINK);
        gemm_k<<<ROUNDL / 64, 256, 0, stream>>>(
            xlh[nxt], xll[nxt], xlh[cur], xll[cur],
            Whf + (size_t)matL * 32768, Wlf + (size_t)matL * 32768,
            b_nl + (size_t)i * H, xlh[nxt], xll[nxt], NLINK);
        // node relation: agg from OLD link feats (xl*[cur]) -> node output buffer
        agg_k<<<(NNODE + 15) / 16, 256, 0, stream>>>(
            xlh[cur], xll[cur], rowp_node, col_ln, xnh[nxt], xnl[nxt], NNODE);
        gemm_k<<<ROUNDN / 64, 256, 0, stream>>>(
            xnh[nxt], xnl[nxt], xnh[cur], xnl[cur],
            Whf + (size_t)matN * 32768, Wlf + (size_t)matN * 32768,
            b_ln + (size_t)i * H, xnh[nxt], xnl[nxt], NNODE);
        cur = nxt;
    }

    pool_k<<<NGRAPH * 8, 256, 0, stream>>>(xlh[cur], xll[cur], gstart, ginv, out);
}